// Round 9
// baseline (153.105 us; speedup 1.0000x reference)
//
#include <hip/hip_runtime.h>
#include <hip/hip_bf16.h>
#include <stdint.h>

// KANLinear fused MFMA GEMM, R9: A-fragments computed IN-REGISTER per lane
// (no A LDS, no A barrier coupling). C = A @ W^T, A = [silu(x) | bspline(x)].
// Wave tile 32x128: lane (l15,q) computes input i=c*8+ks*4+q's 8 coefs for its
// 2 rows -> exactly the MFMA A-operand fragment. B (Wc, L2-resident) is LDS
// double-buffered via global_load_lds with XOR swizzle (0-conflict).
// Block 64x256 (4 waves), grid 512 = 2 blocks/CU for barrier overlap.
// K-order: 32 basis chunks first (x prefetch pipelined), 4 silu chunks last.

#define IN_F 256
#define OUT_F 256
#define KDIM 2304
#define BK 64
#define NCHUNK 36
#define WC_BYTES ((size_t)OUT_F * KDIM * 2)

#define AS1 __attribute__((address_space(1)))
#define AS3 __attribute__((address_space(3)))

typedef float f32x4 __attribute__((ext_vector_type(4)));
typedef short bf16x8 __attribute__((ext_vector_type(8)));

union U4B8 { uint4 u; bf16x8 v; };

__device__ __forceinline__ uint32_t f2bf(float f) {
    union { float f; uint32_t u; } c; c.f = f;
    uint32_t u = c.u;
    return (u + 0x7FFFu + ((u >> 16) & 1u)) >> 16;   // RNE
}

__device__ __forceinline__ float silu_f(float v) {
    return v / (1.0f + __expf(-v));
}

// all 8 spline coefs of one input, packed as the MFMA A-fragment (bf16x8)
__device__ __forceinline__ bf16x8 basis_frag(float xx) {
    float u = __builtin_fmaf(xx, 2.5f, 5.5f);     // (x - grid0)/h
    float jf = floorf(u);
    float t = u - jf;
    int j0 = (int)jf;
    float t2 = t * t, t3 = t2 * t;
    float p3 = t3 * (1.0f / 6.0f);
    float p2 = -0.5f * t3 + 0.5f * t2 + 0.5f * t + (1.0f / 6.0f);
    float p1 = 0.5f * t3 - t2 + (2.0f / 3.0f);
    float omt = 1.0f - t;
    float p0 = omt * omt * omt * (1.0f / 6.0f);
    uint64_t pk = (uint64_t)f2bf(p0) | ((uint64_t)f2bf(p1) << 16) |
                  ((uint64_t)f2bf(p2) << 32) | ((uint64_t)f2bf(p3) << 48);
    if ((unsigned)j0 > 10u) pk = 0ull;
    int jc = j0 < 0 ? 0 : (j0 > 10 ? 10 : j0);
    int sh = jc * 16 - 48;
    unsigned __int128 v = (unsigned __int128)pk;
    v = (sh >= 0) ? (v << sh) : (v >> (-sh));
    U4B8 r;
    r.u.x = (uint32_t)v;
    r.u.y = (uint32_t)(v >> 32);
    r.u.z = (uint32_t)(v >> 64);
    r.u.w = (uint32_t)(v >> 96);
    return r.v;
}

__device__ __forceinline__ bf16x8 silu_frag(const float* p) {
    float4 a = *reinterpret_cast<const float4*>(p);
    float4 b = *reinterpret_cast<const float4*>(p + 4);
    U4B8 r;
    r.u.x = f2bf(silu_f(a.x)) | (f2bf(silu_f(a.y)) << 16);
    r.u.y = f2bf(silu_f(a.z)) | (f2bf(silu_f(a.w)) << 16);
    r.u.z = f2bf(silu_f(b.x)) | (f2bf(silu_f(b.y)) << 16);
    r.u.w = f2bf(silu_f(b.z)) | (f2bf(silu_f(b.w)) << 16);
    return r.v;
}

// ---------------- kernel 1: combined bf16 weight ----------------
__global__ void build_w(const float* __restrict__ bw, const float* __restrict__ sw,
                        const float* __restrict__ ss, unsigned short* __restrict__ Wc) {
    const int o = blockIdx.x;
    const int i = threadIdx.x;
    Wc[o * KDIM + i] = (unsigned short)f2bf(bw[o * IN_F + i]);
    const float scal = ss[o * IN_F + i];
    const float4* swv = reinterpret_cast<const float4*>(sw + (size_t)(o * IN_F + i) * 8);
    float4 s0 = swv[0], s1 = swv[1];
    uint4 wv;
    wv.x = f2bf(s0.x * scal) | (f2bf(s0.y * scal) << 16);
    wv.y = f2bf(s0.z * scal) | (f2bf(s0.w * scal) << 16);
    wv.z = f2bf(s1.x * scal) | (f2bf(s1.y * scal) << 16);
    wv.w = f2bf(s1.z * scal) | (f2bf(s1.w * scal) << 16);
    *reinterpret_cast<uint4*>(Wc + o * KDIM + IN_F + i * 8) = wv;
}

// ---------------- kernel 2: fused GEMM, in-register A ----------------
// B LDS layout: addr(row, g) = row*64 halfwords + ((g ^ (row&7))*8), g = k/8
__launch_bounds__(256, 2)
__global__ void kan_fused(const float* __restrict__ x, const unsigned short* __restrict__ Wc,
                          float* __restrict__ out) {
    __shared__ __align__(16) unsigned short Bs0[256 * 64];
    __shared__ __align__(16) unsigned short Bs1[256 * 64];

    const int row0 = blockIdx.x * 64;
    const int tid = threadIdx.x;
    const int lane = tid & 63;
    const int w = tid >> 6;            // wave 0..3
    const int wm = w >> 1;             // 0..1 : 32-row half
    const int wn = w & 1;              // 0..1 : 128-col half
    const int l15 = lane & 15;
    const int q = lane >> 4;

    // B staging: wave w covers weight rows w*64..w*64+63 (8 instrs of 8 rows x 8 segs)
    const int sr = lane >> 3;
    const int s  = lane & 7;
    const int g  = s ^ sr;             // XOR swizzle: logical k-segment
    const int brow = w * 64 + sr;

    // x row pointers for this lane's two A-row groups (rg=0: l15, rg=1: l15+16)
    const float* xrow0 = x + (size_t)(row0 + wm * 32 + l15) * IN_F;
    const float* xrow1 = xrow0 + 16 * IN_F;

    f32x4 acc[2][8] = {};
    float xA[4], xB[4];                // ping-pong prefetched x: [rg*2+ks]

    auto stage_b = [&](int c, unsigned short* Bsb) {
        const int colbase = (c < 32) ? (256 + c * 64) : ((c - 32) * 64);
        const unsigned short* src = Wc + (size_t)brow * KDIM + colbase + g * 8;
#pragma unroll
        for (int j = 0; j < 8; ++j) {
            __builtin_amdgcn_global_load_lds((const AS1 void*)(src + (size_t)j * 8 * KDIM),
                                             (AS3 void*)&Bsb[(w * 64 + j * 8) * 64],
                                             16, 0, 0);
        }
    };
    auto prefetch_x = [&](int c, float* xs) {
        const int i0 = c * 8 + q;
        xs[0] = xrow0[i0];
        xs[1] = xrow0[i0 + 4];
        xs[2] = xrow1[i0];
        xs[3] = xrow1[i0 + 4];
    };
    auto do_chunk = [&](int c, const unsigned short* Bsb, const float* xs) {
#pragma unroll
        for (int ks = 0; ks < 2; ++ks) {
            bf16x8 af0, af1;
            if (c < 32) {
                af0 = basis_frag(xs[ks]);
                af1 = basis_frag(xs[2 + ks]);
            } else {
                const int off = (c - 32) * 64 + ks * 32 + q * 8;
                af0 = silu_frag(xrow0 + off);
                af1 = silu_frag(xrow1 + off);
            }
            const int g0 = ks * 4 + q;
            bf16x8 bfv[8];
#pragma unroll
            for (int nt = 0; nt < 8; ++nt) {
                int r = wn * 128 + nt * 16 + l15;
                bfv[nt] = *reinterpret_cast<const bf16x8*>(
                    &Bsb[r * 64 + ((g0 ^ (r & 7)) << 3)]);
            }
#pragma unroll
            for (int nt = 0; nt < 8; ++nt) {
                acc[0][nt] = __builtin_amdgcn_mfma_f32_16x16x32_bf16(af0, bfv[nt], acc[0][nt], 0, 0, 0);
                acc[1][nt] = __builtin_amdgcn_mfma_f32_16x16x32_bf16(af1, bfv[nt], acc[1][nt], 0, 0, 0);
            }
        }
    };

    // prologue
    stage_b(0, Bs0);
    prefetch_x(0, xA);
    __syncthreads();

#pragma unroll 1
    for (int it = 0; it < NCHUNK / 2; ++it) {
        const int c0 = it * 2;
        if (c0 + 1 < NCHUNK) {
            stage_b(c0 + 1, Bs1);
            if (c0 + 1 < 32) prefetch_x(c0 + 1, xB);
        }
        do_chunk(c0, Bs0, xA);
        __syncthreads();
        if (c0 + 2 < NCHUNK) {
            stage_b(c0 + 2, Bs0);
            if (c0 + 2 < 32) prefetch_x(c0 + 2, xA);
        }
        do_chunk(c0 + 1, Bs1, xB);
        __syncthreads();
    }

    // epilogue: C/D layout col = lane&15, row = (lane>>4)*4 + reg
    float* outp = out + (size_t)(row0 + wm * 32 + q * 4) * OUT_F + wn * 128 + l15;
#pragma unroll
    for (int rg = 0; rg < 2; ++rg) {
#pragma unroll
        for (int nt = 0; nt < 8; ++nt) {
#pragma unroll
            for (int r = 0; r < 4; ++r)
                outp[(size_t)(rg * 16 + r) * OUT_F + nt * 16] = acc[rg][nt][r];
        }
    }
}

extern "C" void kernel_launch(void* const* d_in, const int* in_sizes, int n_in,
                              void* d_out, int out_size, void* d_ws, size_t ws_size,
                              hipStream_t stream) {
    const float* x  = (const float*)d_in[0];
    const float* bw = (const float*)d_in[1];
    const float* sw = (const float*)d_in[2];
    const float* ss = (const float*)d_in[3];
    unsigned short* Wc = (unsigned short*)d_ws;   // 1.18 MB

    build_w<<<dim3(OUT_F), dim3(IN_F), 0, stream>>>(bw, sw, ss, Wc);

    const int B_ROWS = in_sizes[0] / IN_F;        // 32768
    kan_fused<<<dim3(B_ROWS / 64), dim3(256), 0, stream>>>(x, Wc, (float*)d_out);
}